// Round 3
// baseline (248.624 us; speedup 1.0000x reference)
//
#include <hip/hip_runtime.h>
#include <hip/hip_bf16.h>
#include <stdint.h>

// Problem constants: B=4, S=1024, E=512, H=8, D=64
#define S_LEN 1024
#define E_DIM 512
#define H_NUM 8
#define D_DIM 64
#define B_NUM 4
#define BH_NUM 32

using s16x8 = __attribute__((ext_vector_type(8))) short;           // 8 bf16 (4 VGPRs)
using f32x4 = __attribute__((ext_vector_type(4))) float;           // MFMA accumulator
using us4   = __attribute__((ext_vector_type(4))) unsigned short;  // 4 bf16 (8 B)

static __device__ __forceinline__ unsigned short f2bf(float f) {
  __hip_bfloat16 h = __float2bfloat16(f);
  return __builtin_bit_cast(unsigned short, h);
}

// ---------------------------------------------------------------------------
// K_PREP: fused recurrence + pack + transpose (block-range dispatch).
//   blocks [0,8):        recurrence, one thread per (b,h,d) chain
//   blocks [8,2056):     pack src/tgt -> (bh,s,d) bf16 (4 elts/thread, vec)
//   blocks [2056,2568):  transpose tgt -> (b,e,s) bf16
// ---------------------------------------------------------------------------
#define NB_RECUR 8
#define NB_PACK  2048
#define NB_TR    512

__global__ __launch_bounds__(256) void k_prep(const float* __restrict__ src,
                                              const float* __restrict__ tgt,
                                              const float* __restrict__ enc,
                                              __hip_bfloat16* __restrict__ qb,
                                              __hip_bfloat16* __restrict__ kb,
                                              __hip_bfloat16* __restrict__ cb,
                                              __hip_bfloat16* __restrict__ tT) {
  __shared__ float tile[64][65];                   // used by transpose branch only
  const int bid = blockIdx.x;
  const int tid = threadIdx.x;

  if (bid < NB_RECUR) {
    // ---- serial recurrence: c_t = tanh(cc*pe); cc' = k_t*c_t; cc_0 = k_0 ----
    int g = bid * 256 + tid;                       // 0..2047
    int d = g & 63;
    int bh = g >> 6;
    int h = bh & 7;
    int b = bh >> 3;
    float pe = enc[h * D_DIM + d];
    float pe2 = 2.0f * pe;                         // tanh(x)=sgn(x)(1-e)/(1+e), e=exp(-2|x|)
    const float* tp = tgt + (size_t)b * S_LEN * E_DIM + h * D_DIM + d;
    __hip_bfloat16* cp = cb + (size_t)bh * S_LEN * D_DIM + d;

    constexpr int CH = 32;                         // prefetch chunk (registers)
    float bufA[CH], bufB[CH];
#pragma unroll
    for (int i = 0; i < CH; ++i) bufA[i] = tp[(size_t)i * E_DIM];
    float cc = bufA[0];                            // carry_0 = k_0

#pragma unroll 1
    for (int ch = 0; ch < S_LEN / CH; ch += 2) {
      if (ch + 1 < S_LEN / CH) {
#pragma unroll
        for (int i = 0; i < CH; ++i)
          bufB[i] = tp[(size_t)((ch + 1) * CH + i) * E_DIM];
      }
#pragma unroll
      for (int i = 0; i < CH; ++i) {
        float m = cc * pe2;
        float e = __expf(-fabsf(m));               // abs/neg fold to input mods
        float th = __builtin_copysignf((1.0f - e) * __builtin_amdgcn_rcpf(1.0f + e), m);
        cp[(size_t)(ch * CH + i) * D_DIM] = __float2bfloat16(th);
        cc = bufA[i] * th;
      }
      if (ch + 2 < S_LEN / CH) {
#pragma unroll
        for (int i = 0; i < CH; ++i)
          bufA[i] = tp[(size_t)((ch + 2) * CH + i) * E_DIM];
      }
#pragma unroll
      for (int i = 0; i < CH; ++i) {
        float m = cc * pe2;
        float e = __expf(-fabsf(m));
        float th = __builtin_copysignf((1.0f - e) * __builtin_amdgcn_rcpf(1.0f + e), m);
        cp[(size_t)((ch + 1) * CH + i) * D_DIM] = __float2bfloat16(th);
        cc = bufB[i] * th;
      }
    }
  } else if (bid < NB_RECUR + NB_PACK) {
    // ---- pack src/tgt (b,s,e) fp32 -> (bh,s,d) bf16, 4 elts/thread ----
    size_t i4 = ((size_t)(bid - NB_RECUR) * 256 + tid) * 4;   // < 2M
    float4 s4 = *reinterpret_cast<const float4*>(src + i4);
    float4 t4 = *reinterpret_cast<const float4*>(tgt + i4);
    int e = (int)(i4 & 511);                       // e%4==0, within one head (D=64)
    size_t bs = i4 >> 9;
    int s = (int)(bs & 1023);
    int b = (int)(bs >> 10);
    int h = e >> 6, d = e & 63;
    size_t o = (((size_t)(b * H_NUM + h) * S_LEN) + s) * D_DIM + d;
    us4 qv = {f2bf(s4.x), f2bf(s4.y), f2bf(s4.z), f2bf(s4.w)};
    us4 kv = {f2bf(t4.x), f2bf(t4.y), f2bf(t4.z), f2bf(t4.w)};
    *reinterpret_cast<us4*>(qb + o) = qv;
    *reinterpret_cast<us4*>(kb + o) = kv;
  } else {
    // ---- transpose tgt (b,s,e) -> tT (b,e,s) bf16, 64x64 tiles ----
    int lb = bid - (NB_RECUR + NB_PACK);           // 0..511
    int sx = lb & 15, ey = (lb >> 4) & 7, b = lb >> 7;
    int e0 = ey * 64, s0 = sx * 64;
    int tx = tid & 63, ty = tid >> 6;              // ty 0..3
    const float* p = tgt + ((size_t)b * S_LEN + s0) * E_DIM + e0;
#pragma unroll
    for (int r = ty; r < 64; r += 4) tile[r][tx] = p[(size_t)r * E_DIM + tx];
    __syncthreads();
    __hip_bfloat16* q = tT + ((size_t)b * E_DIM + e0) * S_LEN + s0;
#pragma unroll
    for (int r = ty; r < 64; r += 4) q[(size_t)r * S_LEN + tx] = __float2bfloat16(tile[tx][r]);
  }
}

// ---------------------------------------------------------------------------
// K3: attention weights — register-resident strip (no LDS round-trip).
// Block = 256 thr (4 waves) handles (bh, 16 s-rows); wave owns a 256-wide
// t-quarter. Lane (col=lane&15, quad=lane>>4) holds C-cells
// (s = s0+quad*4+i, t = t0+col) — IDENTICAL cells in both GEMMs, so the
// g~ strip lives in 64 fp32 registers between passes.
//  P1: g~ = exp(QC^T/8) -> regs, reduce l_g
//  P2: w~ = exp(sa*QK^T + sb*g~*ilg) -> regs (overwrite), reduce l_w
//  P3: w = w~ * ilw -> wt in (bh, t, s) bf16 layout
// No max-subtraction: logits bounded (|qc|/8 <= ~9, z < 1).
// ---------------------------------------------------------------------------
__global__ __launch_bounds__(256) void k_weights(const __hip_bfloat16* __restrict__ qb,
                                                 const __hip_bfloat16* __restrict__ kb,
                                                 const __hip_bfloat16* __restrict__ cb,
                                                 __hip_bfloat16* __restrict__ wt,
                                                 const float* __restrict__ pal,
                                                 const float* __restrict__ pbe,
                                                 const float* __restrict__ pga) {
  __shared__ float red0[4][16];                    // per-wave l_g partials
  __shared__ float red1[4][16];                    // per-wave l_w partials

  const int tid = threadIdx.x;
  const int wave = tid >> 6, lane = tid & 63;
  const int quad = lane >> 4, col = lane & 15;
  const int bh = blockIdx.y;
  const int s0 = blockIdx.x * 16;

  const float alpha = pal[0], beta = pbe[0];
  const float inv_gamma = 1.0f / pga[0];
  const float sa = alpha * 0.01f * inv_gamma;      // semantic scale folded
  const float sb = beta * inv_gamma;

  // A fragments (Q rows s0..s0+15), loaded once, shared by both GEMMs.
  const __hip_bfloat16* qrow = qb + ((size_t)bh * S_LEN + s0 + col) * D_DIM;
  s16x8 a0 = *reinterpret_cast<const s16x8*>(qrow + quad * 8);
  s16x8 a1 = *reinterpret_cast<const s16x8*>(qrow + 32 + quad * 8);

  const int t_base = wave * 256;
  float st[16][4];                                 // register strip: 64 fp32

  // ---- pass 1: grammar exp -> regs + l_g ----
  const __hip_bfloat16* cbh = cb + ((size_t)bh * S_LEN + t_base + col) * D_DIM;
  float lg[4] = {0.f, 0.f, 0.f, 0.f};
#pragma unroll
  for (int it = 0; it < 16; ++it) {
    const __hip_bfloat16* crow = cbh + (size_t)it * 16 * D_DIM;
    s16x8 b0 = *reinterpret_cast<const s16x8*>(crow + quad * 8);
    s16x8 b1 = *reinterpret_cast<const s16x8*>(crow + 32 + quad * 8);
    f32x4 dacc = {0.f, 0.f, 0.f, 0.f};
    dacc = __builtin_amdgcn_mfma_f32_16x16x32_bf16(a0, b0, dacc, 0, 0, 0);
    dacc = __builtin_amdgcn_mfma_f32_16x16x32_bf16(a1, b1, dacc, 0, 0, 0);
#pragma unroll
    for (int i = 0; i < 4; ++i) {
      float g = __expf(dacc[i] * 0.125f);          // /sqrt(D)
      st[it][i] = g;
      lg[i] += g;
    }
  }
#pragma unroll
  for (int m = 1; m < 16; m <<= 1) {
#pragma unroll
    for (int i = 0; i < 4; ++i) lg[i] += __shfl_xor(lg[i], m);
  }
  if (col == 0) {
#pragma unroll
    for (int i = 0; i < 4; ++i) red0[wave][quad * 4 + i] = lg[i];
  }
  __syncthreads();
  float ilg[4];
#pragma unroll
  for (int i = 0; i < 4; ++i) {
    int r = quad * 4 + i;
    ilg[i] = 1.0f / (red0[0][r] + red0[1][r] + red0[2][r] + red0[3][r]);
  }

  // ---- pass 2: semantic + combine -> regs + l_w ----
  const __hip_bfloat16* kbh = kb + ((size_t)bh * S_LEN + t_base + col) * D_DIM;
  float lw[4] = {0.f, 0.f, 0.f, 0.f};
#pragma unroll
  for (int it = 0; it < 16; ++it) {
    const __hip_bfloat16* krow = kbh + (size_t)it * 16 * D_DIM;
    s16x8 b0 = *reinterpret_cast<const s16x8*>(krow + quad * 8);
    s16x8 b1 = *reinterpret_cast<const s16x8*>(krow + 32 + quad * 8);
    f32x4 dacc = {0.f, 0.f, 0.f, 0.f};
    dacc = __builtin_amdgcn_mfma_f32_16x16x32_bf16(a0, b0, dacc, 0, 0, 0);
    dacc = __builtin_amdgcn_mfma_f32_16x16x32_bf16(a1, b1, dacc, 0, 0, 0);
#pragma unroll
    for (int i = 0; i < 4; ++i) {
      float z = sa * dacc[i] + sb * (st[it][i] * ilg[i]);
      float wv = __expf(z);
      st[it][i] = wv;
      lw[i] += wv;
    }
  }
#pragma unroll
  for (int m = 1; m < 16; m <<= 1) {
#pragma unroll
    for (int i = 0; i < 4; ++i) lw[i] += __shfl_xor(lw[i], m);
  }
  if (col == 0) {
#pragma unroll
    for (int i = 0; i < 4; ++i) red1[wave][quad * 4 + i] = lw[i];
  }
  __syncthreads();
  float ilw[4];
#pragma unroll
  for (int i = 0; i < 4; ++i) {
    int r = quad * 4 + i;
    ilw[i] = 1.0f / (red1[0][r] + red1[1][r] + red1[2][r] + red1[3][r]);
  }

  // ---- pass 3: normalize + write wt (t, s) layout ----
  __hip_bfloat16* wrow = wt + ((size_t)bh * S_LEN + t_base + col) * S_LEN + s0 + quad * 4;
#pragma unroll
  for (int it = 0; it < 16; ++it) {
    us4 o;
#pragma unroll
    for (int i = 0; i < 4; ++i) o[i] = f2bf(st[it][i] * ilw[i]);
    *reinterpret_cast<us4*>(wrow + (size_t)it * 16 * S_LEN) = o;
  }
}

// ---------------------------------------------------------------------------
// K4: out[bh, t, e] = sum_s wt[bh][t][s] * tT[b][e][s]   (BT-GEMM, m97 style)
// Tile 128(m=t) x 128(n=e), BK=64(k=s). 256 thr; wave -> 64x64 subtile.
// 1D grid with XCD-aware swizzle: the 4 n-tiles sharing one wt A-strip get
// linear ids {x, x+8, x+16, x+24} -> same XCD under round-robin dispatch,
// so the 256 KB strip is fetched into one L2, not four. Each XCD also only
// touches 4 bh values -> tT (1 MB/b) stays L2-resident.
// ---------------------------------------------------------------------------
typedef const __attribute__((address_space(1))) uint32_t gas_uint;
typedef __attribute__((address_space(3))) uint32_t las_uint;

__global__ __launch_bounds__(256) void k_outgemm(const __hip_bfloat16* __restrict__ wt,
                                                 const __hip_bfloat16* __restrict__ tT,
                                                 float* __restrict__ out) {
  __shared__ __hip_bfloat16 As[128 * 64];          // [m][k] 16 KB
  __shared__ __hip_bfloat16 Bs[128 * 64];          // [n][k] 16 KB
  const int tid = threadIdx.x;
  const int wave = tid >> 6, lane = tid & 63;
  const int quad = lane >> 4, col = lane & 15;

  const int g = blockIdx.x;                        // 0..1023
  const int xcd = g & 7;
  const int local = g >> 3;                        // 0..127
  const int strip = xcd * 32 + (local >> 2);       // 0..255 = (bh, mtile)
  const int ntile = local & 3;
  const int bh = strip >> 3;
  const int mt = strip & 7;
  const int b = bh >> 3;
  const int m0 = mt * 128;                         // t
  const int n0 = ntile * 128;                      // e

  const __hip_bfloat16* Ag = wt + (size_t)bh * S_LEN * S_LEN;   // row stride S
  const __hip_bfloat16* Bg = tT + (size_t)b * E_DIM * S_LEN;    // row stride S
  const int mw = (wave >> 1) * 64, nw = (wave & 1) * 64;
  const int lrow = lane >> 3;                      // 0..7
  const int lcol = (lane & 7) * 8;                 // element col offset

  f32x4 acc[4][4];
#pragma unroll
  for (int i = 0; i < 4; ++i)
#pragma unroll
    for (int j = 0; j < 4; ++j) acc[i][j] = (f32x4){0.f, 0.f, 0.f, 0.f};

  for (int kt = 0; kt < 16; ++kt) {
    const int k0 = kt * 64;
    __syncthreads();                               // protect LDS from prior reads
#pragma unroll
    for (int j = 0; j < 4; ++j) {                  // stage A: 4x16B per thread
      int row = j * 32 + wave * 8 + lrow;
      const __hip_bfloat16* gp = Ag + (size_t)(m0 + row) * S_LEN + k0 + lcol;
      __builtin_amdgcn_global_load_lds((gas_uint*)gp,
                                       (las_uint*)(As + (j * 32 + wave * 8) * 64),
                                       16, 0, 0);
    }
#pragma unroll
    for (int j = 0; j < 4; ++j) {                  // stage B
      int row = j * 32 + wave * 8 + lrow;
      const __hip_bfloat16* gp = Bg + (size_t)(n0 + row) * S_LEN + k0 + lcol;
      __builtin_amdgcn_global_load_lds((gas_uint*)gp,
                                       (las_uint*)(Bs + (j * 32 + wave * 8) * 64),
                                       16, 0, 0);
    }
    __syncthreads();                               // drain vmcnt + barrier
#pragma unroll
    for (int ks = 0; ks < 2; ++ks) {
      s16x8 af[4], bf[4];
#pragma unroll
      for (int i = 0; i < 4; ++i)
        af[i] = *reinterpret_cast<const s16x8*>(As + (mw + i * 16 + col) * 64 + ks * 32 + quad * 8);
#pragma unroll
      for (int i = 0; i < 4; ++i)
        bf[i] = *reinterpret_cast<const s16x8*>(Bs + (nw + i * 16 + col) * 64 + ks * 32 + quad * 8);
#pragma unroll
      for (int mi = 0; mi < 4; ++mi)
#pragma unroll
        for (int ni = 0; ni < 4; ++ni)
          acc[mi][ni] = __builtin_amdgcn_mfma_f32_16x16x32_bf16(af[mi], bf[ni], acc[mi][ni], 0, 0, 0);
    }
  }

  // epilogue: C row = quad*4+reg (m), col = lane&15 (n)
#pragma unroll
  for (int mi = 0; mi < 4; ++mi)
#pragma unroll
    for (int ni = 0; ni < 4; ++ni)
#pragma unroll
      for (int i = 0; i < 4; ++i) {
        int m = m0 + mw + mi * 16 + quad * 4 + i;
        int n = n0 + nw + ni * 16 + col;
        out[((size_t)bh * S_LEN + m) * E_DIM + n] = acc[mi][ni][i];
      }
}

// ---------------------------------------------------------------------------
// Workspace layout (bytes):
//   qb  [0,   4M)   (BH,S,D) bf16
//   kb  [4M,  8M)
//   cb  [8M, 12M)
//   tT  [12M,16M)   (B,E,S) bf16
//   wt  [16M,80M)   (BH,S_t,S_s) bf16
// ---------------------------------------------------------------------------
extern "C" void kernel_launch(void* const* d_in, const int* in_sizes, int n_in,
                              void* d_out, int out_size, void* d_ws, size_t ws_size,
                              hipStream_t stream) {
  (void)in_sizes; (void)n_in; (void)out_size; (void)ws_size;
  const float* src = (const float*)d_in[0];
  const float* tgt = (const float*)d_in[1];
  const float* enc = (const float*)d_in[2];
  const float* pal = (const float*)d_in[3];
  const float* pbe = (const float*)d_in[4];
  const float* pga = (const float*)d_in[5];
  float* out = (float*)d_out;

  char* ws = (char*)d_ws;
  __hip_bfloat16* qb = (__hip_bfloat16*)(ws);
  __hip_bfloat16* kb = (__hip_bfloat16*)(ws + ((size_t)4 << 20));
  __hip_bfloat16* cb = (__hip_bfloat16*)(ws + ((size_t)8 << 20));
  __hip_bfloat16* tT = (__hip_bfloat16*)(ws + ((size_t)12 << 20));
  __hip_bfloat16* wt = (__hip_bfloat16*)(ws + ((size_t)16 << 20));

  // Fused prep: recurrence (blocks 0..7) + pack + transpose
  k_prep<<<NB_RECUR + NB_PACK + NB_TR, 256, 0, stream>>>(src, tgt, enc, qb, kb, cb, tT);
  // K3: weights
  k_weights<<<dim3(S_LEN / 16, BH_NUM), 256, 0, stream>>>(qb, kb, cb, wt, pal, pbe, pga);
  // K4: output GEMM (1D swizzled grid)
  k_outgemm<<<dim3((E_DIM / 128) * (S_LEN / 128) * BH_NUM), 256, 0, stream>>>(wt, tT, out);
}

// Round 4
// 245.925 us; speedup vs baseline: 1.0110x; 1.0110x over previous
//
#include <hip/hip_runtime.h>
#include <hip/hip_bf16.h>
#include <stdint.h>

// Problem constants: B=4, S=1024, E=512, H=8, D=64
#define S_LEN 1024
#define E_DIM 512
#define H_NUM 8
#define D_DIM 64
#define B_NUM 4
#define BH_NUM 32

using s16x8 = __attribute__((ext_vector_type(8))) short;           // 8 bf16 (4 VGPRs)
using f32x4 = __attribute__((ext_vector_type(4))) float;           // MFMA accumulator
using us4   = __attribute__((ext_vector_type(4))) unsigned short;  // 4 bf16 (8 B)

static __device__ __forceinline__ unsigned short f2bf(float f) {
  __hip_bfloat16 h = __float2bfloat16(f);
  return __builtin_bit_cast(unsigned short, h);
}
static __device__ __forceinline__ float bf2f(unsigned short u) {
  return __bfloat162float(__builtin_bit_cast(__hip_bfloat16, u));
}

// ---------------------------------------------------------------------------
// K_PREP: fused recurrence + pack + transpose (block-range dispatch).
// ---------------------------------------------------------------------------
#define NB_RECUR 8
#define NB_PACK  2048
#define NB_TR    512

__global__ __launch_bounds__(256) void k_prep(const float* __restrict__ src,
                                              const float* __restrict__ tgt,
                                              const float* __restrict__ enc,
                                              __hip_bfloat16* __restrict__ qb,
                                              __hip_bfloat16* __restrict__ kb,
                                              __hip_bfloat16* __restrict__ cb,
                                              __hip_bfloat16* __restrict__ tT) {
  __shared__ float tile[64][65];                   // used by transpose branch only
  const int bid = blockIdx.x;
  const int tid = threadIdx.x;

  if (bid < NB_RECUR) {
    // ---- serial recurrence: c_t = tanh(cc*pe); cc' = k_t*c_t; cc_0 = k_0 ----
    int g = bid * 256 + tid;                       // 0..2047
    int d = g & 63;
    int bh = g >> 6;
    int h = bh & 7;
    int b = bh >> 3;
    float pe = enc[h * D_DIM + d];
    float pe2 = 2.0f * pe;                         // tanh(x)=sgn(x)(1-e)/(1+e), e=exp(-2|x|)
    const float* tp = tgt + (size_t)b * S_LEN * E_DIM + h * D_DIM + d;
    __hip_bfloat16* cp = cb + (size_t)bh * S_LEN * D_DIM + d;

    constexpr int CH = 32;                         // prefetch chunk (registers)
    float bufA[CH], bufB[CH];
#pragma unroll
    for (int i = 0; i < CH; ++i) bufA[i] = tp[(size_t)i * E_DIM];
    float cc = bufA[0];                            // carry_0 = k_0

#pragma unroll 1
    for (int ch = 0; ch < S_LEN / CH; ch += 2) {
      if (ch + 1 < S_LEN / CH) {
#pragma unroll
        for (int i = 0; i < CH; ++i)
          bufB[i] = tp[(size_t)((ch + 1) * CH + i) * E_DIM];
      }
#pragma unroll
      for (int i = 0; i < CH; ++i) {
        float m = cc * pe2;
        float e = __expf(-fabsf(m));               // abs/neg fold to input mods
        float th = __builtin_copysignf((1.0f - e) * __builtin_amdgcn_rcpf(1.0f + e), m);
        cp[(size_t)(ch * CH + i) * D_DIM] = __float2bfloat16(th);
        cc = bufA[i] * th;
      }
      if (ch + 2 < S_LEN / CH) {
#pragma unroll
        for (int i = 0; i < CH; ++i)
          bufA[i] = tp[(size_t)((ch + 2) * CH + i) * E_DIM];
      }
#pragma unroll
      for (int i = 0; i < CH; ++i) {
        float m = cc * pe2;
        float e = __expf(-fabsf(m));
        float th = __builtin_copysignf((1.0f - e) * __builtin_amdgcn_rcpf(1.0f + e), m);
        cp[(size_t)((ch + 1) * CH + i) * D_DIM] = __float2bfloat16(th);
        cc = bufB[i] * th;
      }
    }
  } else if (bid < NB_RECUR + NB_PACK) {
    // ---- pack src/tgt (b,s,e) fp32 -> (bh,s,d) bf16, 4 elts/thread ----
    size_t i4 = ((size_t)(bid - NB_RECUR) * 256 + tid) * 4;   // < 2M
    float4 s4 = *reinterpret_cast<const float4*>(src + i4);
    float4 t4 = *reinterpret_cast<const float4*>(tgt + i4);
    int e = (int)(i4 & 511);                       // e%4==0, within one head (D=64)
    size_t bs = i4 >> 9;
    int s = (int)(bs & 1023);
    int b = (int)(bs >> 10);
    int h = e >> 6, d = e & 63;
    size_t o = (((size_t)(b * H_NUM + h) * S_LEN) + s) * D_DIM + d;
    us4 qv = {f2bf(s4.x), f2bf(s4.y), f2bf(s4.z), f2bf(s4.w)};
    us4 kv = {f2bf(t4.x), f2bf(t4.y), f2bf(t4.z), f2bf(t4.w)};
    *reinterpret_cast<us4*>(qb + o) = qv;
    *reinterpret_cast<us4*>(kb + o) = kv;
  } else {
    // ---- transpose tgt (b,s,e) -> tT (b,e,s) bf16, 64x64 tiles ----
    int lb = bid - (NB_RECUR + NB_PACK);           // 0..511
    int sx = lb & 15, ey = (lb >> 4) & 7, b = lb >> 7;
    int e0 = ey * 64, s0 = sx * 64;
    int tx = tid & 63, ty = tid >> 6;              // ty 0..3
    const float* p = tgt + ((size_t)b * S_LEN + s0) * E_DIM + e0;
#pragma unroll
    for (int r = ty; r < 64; r += 4) tile[r][tx] = p[(size_t)r * E_DIM + tx];
    __syncthreads();
    __hip_bfloat16* q = tT + ((size_t)b * E_DIM + e0) * S_LEN + s0;
#pragma unroll
    for (int r = ty; r < 64; r += 4) q[(size_t)r * S_LEN + tx] = __float2bfloat16(tile[tx][r]);
  }
}

// ---------------------------------------------------------------------------
// K3: attention weights — single fused load sweep + XCD-local scheduling.
// 2048 blocks, 1D grid, swizzled so XCD x (= blockIdx%8 under round-robin
// dispatch) handles only bh in [4x, 4x+4): per-XCD working set = 4 x 256 KB
// of cb/kb -> L2-resident -> fragment loads are L2 hits.
// Block: (bh, 16 s-rows); wave owns a 256-wide t-quarter.
//  P1: per it load crow+krow, 4 MFMAs; g~=exp(qc/8) packed bf16 (32 regs),
//      qk kept fp32 (64 regs); reduce l_g.
//  P2 (register-only): z = sa*qk + sb*g~*ilg; w~=exp(z) -> overwrite qk; l_w.
//  P3: w = w~*ilw -> wt (bh, t, s) bf16.
// No max-subtraction: logits bounded (|qc|/8 <= ~9, z < 1).
// ---------------------------------------------------------------------------
__global__ __launch_bounds__(256) void k_weights(const __hip_bfloat16* __restrict__ qb,
                                                 const __hip_bfloat16* __restrict__ kb,
                                                 const __hip_bfloat16* __restrict__ cb,
                                                 __hip_bfloat16* __restrict__ wt,
                                                 const float* __restrict__ pal,
                                                 const float* __restrict__ pbe,
                                                 const float* __restrict__ pga) {
  __shared__ float red0[4][16];                    // per-wave l_g partials
  __shared__ float red1[4][16];                    // per-wave l_w partials

  const int tid = threadIdx.x;
  const int wave = tid >> 6, lane = tid & 63;
  const int quad = lane >> 4, col = lane & 15;

  // XCD-aware decode: xcd = g&7 (round-robin), r enumerates (bh-sub, s-tile)
  const int g = blockIdx.x;
  const int xcd = g & 7;
  const int r = g >> 3;                            // 0..255
  const int bh = xcd * 4 + (r >> 6);               // 4 bh per XCD
  const int s0 = (r & 63) * 16;

  const float alpha = pal[0], beta = pbe[0];
  const float inv_gamma = 1.0f / pga[0];
  const float sa = alpha * 0.01f * inv_gamma;      // semantic scale folded
  const float sb = beta * inv_gamma;

  // A fragments (Q rows s0..s0+15), loaded once, shared by both GEMMs.
  const __hip_bfloat16* qrow = qb + ((size_t)bh * S_LEN + s0 + col) * D_DIM;
  s16x8 a0 = *reinterpret_cast<const s16x8*>(qrow + quad * 8);
  s16x8 a1 = *reinterpret_cast<const s16x8*>(qrow + 32 + quad * 8);

  const int t_base = wave * 256;
  uint32_t stg[16][2];                             // g~ packed bf16 pairs (32 regs)
  float    stk[16][4];                             // qk logits fp32 (64 regs)

  // ---- pass 1: fused QC^T + QK^T sweep ----
  const __hip_bfloat16* cbh = cb + ((size_t)bh * S_LEN + t_base + col) * D_DIM;
  const __hip_bfloat16* kbh = kb + ((size_t)bh * S_LEN + t_base + col) * D_DIM;
  float lg[4] = {0.f, 0.f, 0.f, 0.f};
#pragma unroll
  for (int it = 0; it < 16; ++it) {
    const __hip_bfloat16* crow = cbh + (size_t)it * 16 * D_DIM;
    const __hip_bfloat16* krow = kbh + (size_t)it * 16 * D_DIM;
    s16x8 cb0 = *reinterpret_cast<const s16x8*>(crow + quad * 8);
    s16x8 cb1 = *reinterpret_cast<const s16x8*>(crow + 32 + quad * 8);
    s16x8 kb0 = *reinterpret_cast<const s16x8*>(krow + quad * 8);
    s16x8 kb1 = *reinterpret_cast<const s16x8*>(krow + 32 + quad * 8);
    f32x4 dg = {0.f, 0.f, 0.f, 0.f};
    dg = __builtin_amdgcn_mfma_f32_16x16x32_bf16(a0, cb0, dg, 0, 0, 0);
    dg = __builtin_amdgcn_mfma_f32_16x16x32_bf16(a1, cb1, dg, 0, 0, 0);
    f32x4 dk = {0.f, 0.f, 0.f, 0.f};
    dk = __builtin_amdgcn_mfma_f32_16x16x32_bf16(a0, kb0, dk, 0, 0, 0);
    dk = __builtin_amdgcn_mfma_f32_16x16x32_bf16(a1, kb1, dk, 0, 0, 0);
    uint32_t p0 = 0, p1 = 0;
#pragma unroll
    for (int i = 0; i < 4; ++i) {
      float gv = __expf(dg[i] * 0.125f);           // /sqrt(D)
      unsigned short u = f2bf(gv);
      lg[i] += bf2f(u);                            // sum the ROUNDED value (consistent)
      if (i < 2) p0 |= (uint32_t)u << (16 * i);
      else       p1 |= (uint32_t)u << (16 * (i - 2));
      stk[it][i] = dk[i];
    }
    stg[it][0] = p0;
    stg[it][1] = p1;
  }
#pragma unroll
  for (int m = 1; m < 16; m <<= 1) {
#pragma unroll
    for (int i = 0; i < 4; ++i) lg[i] += __shfl_xor(lg[i], m);
  }
  if (col == 0) {
#pragma unroll
    for (int i = 0; i < 4; ++i) red0[wave][quad * 4 + i] = lg[i];
  }
  __syncthreads();
  float ilg[4];
#pragma unroll
  for (int i = 0; i < 4; ++i) {
    int rr = quad * 4 + i;
    ilg[i] = 1.0f / (red0[0][rr] + red0[1][rr] + red0[2][rr] + red0[3][rr]);
  }

  // ---- pass 2 (register-only): combine + l_w ----
  float lw[4] = {0.f, 0.f, 0.f, 0.f};
#pragma unroll
  for (int it = 0; it < 16; ++it) {
#pragma unroll
    for (int i = 0; i < 4; ++i) {
      unsigned short u = (unsigned short)((i < 2 ? stg[it][0] >> (16 * i)
                                                 : stg[it][1] >> (16 * (i - 2))) & 0xffffu);
      float gv = bf2f(u) * ilg[i];
      float z = sa * stk[it][i] + sb * gv;
      float wv = __expf(z);
      stk[it][i] = wv;
      lw[i] += wv;
    }
  }
#pragma unroll
  for (int m = 1; m < 16; m <<= 1) {
#pragma unroll
    for (int i = 0; i < 4; ++i) lw[i] += __shfl_xor(lw[i], m);
  }
  if (col == 0) {
#pragma unroll
    for (int i = 0; i < 4; ++i) red1[wave][quad * 4 + i] = lw[i];
  }
  __syncthreads();
  float ilw[4];
#pragma unroll
  for (int i = 0; i < 4; ++i) {
    int rr = quad * 4 + i;
    ilw[i] = 1.0f / (red1[0][rr] + red1[1][rr] + red1[2][rr] + red1[3][rr]);
  }

  // ---- pass 3: normalize + write wt (t, s) layout ----
  __hip_bfloat16* wrow = wt + ((size_t)bh * S_LEN + t_base + col) * S_LEN + s0 + quad * 4;
#pragma unroll
  for (int it = 0; it < 16; ++it) {
    us4 o;
#pragma unroll
    for (int i = 0; i < 4; ++i) o[i] = f2bf(stk[it][i] * ilw[i]);
    *reinterpret_cast<us4*>(wrow + (size_t)it * 16 * S_LEN) = o;
  }
}

// ---------------------------------------------------------------------------
// K4: out[bh, t, e] = sum_s wt[bh][t][s] * tT[b][e][s]   (BT-GEMM, m97 style)
// Tile 128(m=t) x 128(n=e), BK=64(k=s). 256 thr; wave -> 64x64 subtile.
// 1D grid with XCD-aware swizzle (wt A-strip + tT locality per XCD).
// ---------------------------------------------------------------------------
typedef const __attribute__((address_space(1))) uint32_t gas_uint;
typedef __attribute__((address_space(3))) uint32_t las_uint;

__global__ __launch_bounds__(256) void k_outgemm(const __hip_bfloat16* __restrict__ wt,
                                                 const __hip_bfloat16* __restrict__ tT,
                                                 float* __restrict__ out) {
  __shared__ __hip_bfloat16 As[128 * 64];          // [m][k] 16 KB
  __shared__ __hip_bfloat16 Bs[128 * 64];          // [n][k] 16 KB
  const int tid = threadIdx.x;
  const int wave = tid >> 6, lane = tid & 63;
  const int quad = lane >> 4, col = lane & 15;

  const int g = blockIdx.x;                        // 0..1023
  const int xcd = g & 7;
  const int local = g >> 3;                        // 0..127
  const int strip = xcd * 32 + (local >> 2);       // 0..255 = (bh, mtile)
  const int ntile = local & 3;
  const int bh = strip >> 3;
  const int mt = strip & 7;
  const int b = bh >> 3;
  const int m0 = mt * 128;                         // t
  const int n0 = ntile * 128;                      // e

  const __hip_bfloat16* Ag = wt + (size_t)bh * S_LEN * S_LEN;   // row stride S
  const __hip_bfloat16* Bg = tT + (size_t)b * E_DIM * S_LEN;    // row stride S
  const int mw = (wave >> 1) * 64, nw = (wave & 1) * 64;
  const int lrow = lane >> 3;                      // 0..7
  const int lcol = (lane & 7) * 8;                 // element col offset

  f32x4 acc[4][4];
#pragma unroll
  for (int i = 0; i < 4; ++i)
#pragma unroll
    for (int j = 0; j < 4; ++j) acc[i][j] = (f32x4){0.f, 0.f, 0.f, 0.f};

  for (int kt = 0; kt < 16; ++kt) {
    const int k0 = kt * 64;
    __syncthreads();                               // protect LDS from prior reads
#pragma unroll
    for (int j = 0; j < 4; ++j) {                  // stage A: 4x16B per thread
      int row = j * 32 + wave * 8 + lrow;
      const __hip_bfloat16* gp = Ag + (size_t)(m0 + row) * S_LEN + k0 + lcol;
      __builtin_amdgcn_global_load_lds((gas_uint*)gp,
                                       (las_uint*)(As + (j * 32 + wave * 8) * 64),
                                       16, 0, 0);
    }
#pragma unroll
    for (int j = 0; j < 4; ++j) {                  // stage B
      int row = j * 32 + wave * 8 + lrow;
      const __hip_bfloat16* gp = Bg + (size_t)(n0 + row) * S_LEN + k0 + lcol;
      __builtin_amdgcn_global_load_lds((gas_uint*)gp,
                                       (las_uint*)(Bs + (j * 32 + wave * 8) * 64),
                                       16, 0, 0);
    }
    __syncthreads();                               // drain vmcnt + barrier
#pragma unroll
    for (int ks = 0; ks < 2; ++ks) {
      s16x8 af[4], bf[4];
#pragma unroll
      for (int i = 0; i < 4; ++i)
        af[i] = *reinterpret_cast<const s16x8*>(As + (mw + i * 16 + col) * 64 + ks * 32 + quad * 8);
#pragma unroll
      for (int i = 0; i < 4; ++i)
        bf[i] = *reinterpret_cast<const s16x8*>(Bs + (nw + i * 16 + col) * 64 + ks * 32 + quad * 8);
#pragma unroll
      for (int mi = 0; mi < 4; ++mi)
#pragma unroll
        for (int ni = 0; ni < 4; ++ni)
          acc[mi][ni] = __builtin_amdgcn_mfma_f32_16x16x32_bf16(af[mi], bf[ni], acc[mi][ni], 0, 0, 0);
    }
  }

  // epilogue: C row = quad*4+reg (m), col = lane&15 (n)
#pragma unroll
  for (int mi = 0; mi < 4; ++mi)
#pragma unroll
    for (int ni = 0; ni < 4; ++ni)
#pragma unroll
      for (int i = 0; i < 4; ++i) {
        int m = m0 + mw + mi * 16 + quad * 4 + i;
        int n = n0 + nw + ni * 16 + col;
        out[((size_t)bh * S_LEN + m) * E_DIM + n] = acc[mi][ni][i];
      }
}

// ---------------------------------------------------------------------------
// Workspace layout (bytes):
//   qb  [0,   4M)   (BH,S,D) bf16
//   kb  [4M,  8M)
//   cb  [8M, 12M)
//   tT  [12M,16M)   (B,E,S) bf16
//   wt  [16M,80M)   (BH,S_t,S_s) bf16
// ---------------------------------------------------------------------------
extern "C" void kernel_launch(void* const* d_in, const int* in_sizes, int n_in,
                              void* d_out, int out_size, void* d_ws, size_t ws_size,
                              hipStream_t stream) {
  (void)in_sizes; (void)n_in; (void)out_size; (void)ws_size;
  const float* src = (const float*)d_in[0];
  const float* tgt = (const float*)d_in[1];
  const float* enc = (const float*)d_in[2];
  const float* pal = (const float*)d_in[3];
  const float* pbe = (const float*)d_in[4];
  const float* pga = (const float*)d_in[5];
  float* out = (float*)d_out;

  char* ws = (char*)d_ws;
  __hip_bfloat16* qb = (__hip_bfloat16*)(ws);
  __hip_bfloat16* kb = (__hip_bfloat16*)(ws + ((size_t)4 << 20));
  __hip_bfloat16* cb = (__hip_bfloat16*)(ws + ((size_t)8 << 20));
  __hip_bfloat16* tT = (__hip_bfloat16*)(ws + ((size_t)12 << 20));
  __hip_bfloat16* wt = (__hip_bfloat16*)(ws + ((size_t)16 << 20));

  // Fused prep: recurrence (blocks 0..7) + pack + transpose
  k_prep<<<NB_RECUR + NB_PACK + NB_TR, 256, 0, stream>>>(src, tgt, enc, qb, kb, cb, tT);
  // K3: weights (1D swizzled grid, 4 bh per XCD)
  k_weights<<<dim3((S_LEN / 16) * BH_NUM), 256, 0, stream>>>(qb, kb, cb, wt, pal, pbe, pga);
  // K4: output GEMM (1D swizzled grid)
  k_outgemm<<<dim3((E_DIM / 128) * (S_LEN / 128) * BH_NUM), 256, 0, stream>>>(wt, tT, out);
}